// Round 2
// baseline (334.700 us; speedup 1.0000x reference)
//
#include <hip/hip_runtime.h>
#include <hip/hip_bf16.h>
#include <cstdint>

// Problem constants
#define TOK   64
#define INF   4096
#define OUTF  11008
#define NBLK  172        // OUTF / 64 output-channels per block
#define KCHUNKS 128      // INF / 32

using bf16x8  = __attribute__((ext_vector_type(8))) __bf16;
using floatx4 = __attribute__((ext_vector_type(4))) float;

union B8u { uint32_t u[4]; uint4 q; bf16x8 v; };

// pack two fp32 into one dword of two truncated bf16 (elem a = low half)
__device__ __forceinline__ uint32_t hi2(float a, float b) {
    return (__float_as_uint(a) >> 16) | (__float_as_uint(b) & 0xffff0000u);
}
// residual after bf16 truncation (exact in fp32)
__device__ __forceinline__ float losub(float x) {
    return x - __uint_as_float(__float_as_uint(x) & 0xffff0000u);
}

// ---------------------------------------------------------------------------
// k_prep_x: fp32 x[64][4096] -> bf16 hi/lo arrays in MFMA A-fragment order.
// uint4 index = (mt*128 + kc)*64 + lane ; element j: x[mt*16+(lane&15)][kc*32+(lane>>4)*8+j]
// ---------------------------------------------------------------------------
__global__ __launch_bounds__(256) void k_prep_x(const float* __restrict__ x,
        unsigned short* __restrict__ xh, unsigned short* __restrict__ xl) {
    int idx  = blockIdx.x * 256 + threadIdx.x;          // 0..262143
    int j    = idx & 7;
    int lane = (idx >> 3) & 63;
    int kc   = (idx >> 9) & 127;
    int mt   = idx >> 16;
    int row  = mt * 16 + (lane & 15);
    int col  = kc * 32 + ((lane >> 4) << 3) + j;
    float v  = x[(size_t)row * INF + col];
    uint32_t u = __float_as_uint(v);
    float lo = losub(v);
    xh[idx] = (unsigned short)(u >> 16);
    xl[idx] = (unsigned short)(__float_as_uint(lo) >> 16);
}

// ---------------------------------------------------------------------------
// k_lora_t: tm[t][r] = sum_k x[t][k] * A[r][k]   (64x16)
// One block per token; x row staged in LDS; A reads coalesced float4.
// ---------------------------------------------------------------------------
__global__ __launch_bounds__(256) void k_lora_t(const float* __restrict__ x,
        const float* __restrict__ A, float* __restrict__ tm) {
    __shared__ float4 xs[INF / 4];
    int t = blockIdx.x, tid = threadIdx.x;
    const float4* xr = (const float4*)(x + (size_t)t * INF);
    for (int i = tid; i < INF / 4; i += 256) xs[i] = xr[i];
    __syncthreads();
    int wv = tid >> 6, lane = tid & 63;
#pragma unroll
    for (int rr = 0; rr < 4; ++rr) {
        int r = wv * 4 + rr;
        const float4* ar = (const float4*)(A + (size_t)r * INF);
        float s = 0.f;
        for (int i = lane; i < INF / 4; i += 64) {
            float4 a = xs[i], b = ar[i];
            s += a.x * b.x + a.y * b.y + a.z * b.z + a.w * b.w;
        }
#pragma unroll
        for (int off = 32; off > 0; off >>= 1) s += __shfl_down(s, off);
        if (lane == 0) tm[t * 16 + r] = s;
    }
}

// ---------------------------------------------------------------------------
// k_main: y = x @ W^T via 16x16x32 bf16 MFMA, fp32 emulated hi/lo:
//   x*w ~= xh*wh + xh*wl + xl*wh
// Depth-4 register ring buffer on W loads for memory-level parallelism.
// ---------------------------------------------------------------------------
template<int QCNT, bool ATOMIC>
__global__ __launch_bounds__(256) void k_main(const float* __restrict__ W,
        const uint4* __restrict__ xh, const uint4* __restrict__ xl,
        const float* __restrict__ scale, float* __restrict__ part,
        float* __restrict__ out) {
    constexpr int KC = KCHUNKS / QCNT;   // kc chunks per block
    int lane = threadIdx.x & 63;
    int wv   = threadIdx.x >> 6;
    int nb   = blockIdx.x % NBLK;
    int q    = blockIdx.x / NBLK;
    int orow = nb * 64 + wv * 16 + (lane & 15);   // this lane's output channel
    int quad = lane >> 4;

    const float* wp = W + (size_t)orow * INF + q * (KC * 32) + quad * 8;
    int xoff = q * KC * 64 + lane;

    floatx4 acc[4] = {};   // 4 token-tiles x 4 fp32

    constexpr int D = 4;   // prefetch depth
    float4 wA[D], wB[D];
#pragma unroll
    for (int d = 0; d < D; ++d) {
        wA[d] = *(const float4*)(wp + d * 32);
        wB[d] = *(const float4*)(wp + d * 32 + 4);
    }

#pragma unroll 1
    for (int base = 0; base < KC; base += D) {
#pragma unroll
        for (int d = 0; d < D; ++d) {
            int kc = base + d;
            // issue x-fragment loads early (L1/L2-hot)
            int xbase = xoff + kc * 64;
            B8u ah[4], al[4];
#pragma unroll
            for (int mt = 0; mt < 4; ++mt) {
                ah[mt].q = xh[mt * 8192 + xbase];
                al[mt].q = xl[mt * 8192 + xbase];
            }
            float4 w0 = wA[d], w1 = wB[d];
            // prefetch W for kc + D
            if (base + D < KC) {
                wA[d] = *(const float4*)(wp + (size_t)(base + D + d) * 32);
                wB[d] = *(const float4*)(wp + (size_t)(base + D + d) * 32 + 4);
            }
            B8u wh, wl;
            wh.u[0] = hi2(w0.x, w0.y);  wh.u[1] = hi2(w0.z, w0.w);
            wh.u[2] = hi2(w1.x, w1.y);  wh.u[3] = hi2(w1.z, w1.w);
            wl.u[0] = hi2(losub(w0.x), losub(w0.y));
            wl.u[1] = hi2(losub(w0.z), losub(w0.w));
            wl.u[2] = hi2(losub(w1.x), losub(w1.y));
            wl.u[3] = hi2(losub(w1.z), losub(w1.w));
#pragma unroll
            for (int mt = 0; mt < 4; ++mt) {
                acc[mt] = __builtin_amdgcn_mfma_f32_16x16x32_bf16(ah[mt].v, wh.v, acc[mt], 0, 0, 0);
                acc[mt] = __builtin_amdgcn_mfma_f32_16x16x32_bf16(ah[mt].v, wl.v, acc[mt], 0, 0, 0);
                acc[mt] = __builtin_amdgcn_mfma_f32_16x16x32_bf16(al[mt].v, wh.v, acc[mt], 0, 0, 0);
            }
        }
    }

    // C/D layout (16x16, m89): col = lane&15 (= channel), row = quad*4 + reg (= token)
#pragma unroll
    for (int mt = 0; mt < 4; ++mt) {
        int token = mt * 16 + quad * 4;
#pragma unroll
        for (int r = 0; r < 4; ++r) {
            if constexpr (ATOMIC) {
                atomicAdd(&out[(size_t)(token + r) * OUTF + orow], scale[orow] * acc[mt][r]);
            } else {
                part[((size_t)q * TOK + token + r) * OUTF + orow] = acc[mt][r];
            }
        }
    }
}

// ---------------------------------------------------------------------------
// k_post: out[t][o] = scale[o]*sum_q part[q][t][o] + sum_r tm[t][r]*B[o][r] + bias[o]
// ---------------------------------------------------------------------------
template<int QCNT>
__global__ __launch_bounds__(256) void k_post(const float* __restrict__ part,
        const float* __restrict__ scale, const float* __restrict__ bias,
        const float* __restrict__ lB, const float* __restrict__ tm,
        float* __restrict__ out) {
    int o = blockIdx.x * 256 + threadIdx.x;
    int t = blockIdx.y;
    if (o >= OUTF) return;
    float s = 0.f;
#pragma unroll
    for (int qq = 0; qq < QCNT; ++qq)
        s += part[((size_t)qq * TOK + t) * OUTF + o];
    const float4* Br = (const float4*)(lB + (size_t)o * 16);
    const float4* tr = (const float4*)(tm + (size_t)t * 16);
    float l = 0.f;
#pragma unroll
    for (int i = 0; i < 4; ++i) {
        float4 b = Br[i], tt = tr[i];
        l += b.x * tt.x + b.y * tt.y + b.z * tt.z + b.w * tt.w;
    }
    out[(size_t)t * OUTF + o] = s * scale[o] + l + bias[o];
}

// Fallback pre-init for the atomic path: out = lora + bias, main adds scale*y.
__global__ __launch_bounds__(256) void k_pre(const float* __restrict__ bias,
        const float* __restrict__ lB, const float* __restrict__ tm,
        float* __restrict__ out) {
    int o = blockIdx.x * 256 + threadIdx.x;
    int t = blockIdx.y;
    if (o >= OUTF) return;
    const float4* Br = (const float4*)(lB + (size_t)o * 16);
    const float4* tr = (const float4*)(tm + (size_t)t * 16);
    float l = 0.f;
#pragma unroll
    for (int i = 0; i < 4; ++i) {
        float4 b = Br[i], tt = tr[i];
        l += b.x * tt.x + b.y * tt.y + b.z * tt.z + b.w * tt.w;
    }
    out[(size_t)t * OUTF + o] = l + bias[o];
}

extern "C" void kernel_launch(void* const* d_in, const int* in_sizes, int n_in,
                              void* d_out, int out_size, void* d_ws, size_t ws_size,
                              hipStream_t stream) {
    const float* x     = (const float*)d_in[0];
    const float* W     = (const float*)d_in[1];
    const float* scale = (const float*)d_in[2];
    const float* lA    = (const float*)d_in[3];
    const float* lB    = (const float*)d_in[4];
    const float* bias  = (const float*)d_in[5];
    float* out = (float*)d_out;

    char* ws = (char*)d_ws;
    unsigned short* xh = (unsigned short*)(ws);            // 512 KB
    unsigned short* xl = (unsigned short*)(ws + 524288);   // 512 KB
    float* tm   = (float*)(ws + 1048576);                  // 4 KB
    float* part = (float*)(ws + 1052672);
    const size_t base_ws = 1052672;
    const size_t need8 = base_ws + 8ull * TOK * OUTF * 4;  // 23.6 MB
    const size_t need4 = base_ws + 4ull * TOK * OUTF * 4;  // 12.3 MB

    k_prep_x<<<1024, 256, 0, stream>>>(x, xh, xl);
    k_lora_t<<<TOK, 256, 0, stream>>>(x, lA, tm);

    if (ws_size >= need8) {
        k_main<8, false><<<NBLK * 8, 256, 0, stream>>>(W, (const uint4*)xh,
                (const uint4*)xl, scale, part, out);
        k_post<8><<<dim3(43, TOK), 256, 0, stream>>>(part, scale, bias, lB, tm, out);
    } else if (ws_size >= need4) {
        k_main<4, false><<<NBLK * 4, 256, 0, stream>>>(W, (const uint4*)xh,
                (const uint4*)xl, scale, part, out);
        k_post<4><<<dim3(43, TOK), 256, 0, stream>>>(part, scale, bias, lB, tm, out);
    } else {
        k_pre<<<dim3(43, TOK), 256, 0, stream>>>(bias, lB, tm, out);
        k_main<8, true><<<NBLK * 8, 256, 0, stream>>>(W, (const uint4*)xh,
                (const uint4*)xl, scale, nullptr, out);
    }
}

// Round 3
// 276.002 us; speedup vs baseline: 1.2127x; 1.2127x over previous
//
#include <hip/hip_runtime.h>
#include <hip/hip_bf16.h>
#include <cstdint>

// Problem constants
#define TOK   64
#define INF   4096
#define OUTF  11008
#define NBLK  172        // OUTF / 64 output-channels per block
#define KCHUNKS 128      // INF / 32

using bf16x8  = __attribute__((ext_vector_type(8))) __bf16;
using floatx4 = __attribute__((ext_vector_type(4))) float;

union B8u { uint32_t u[4]; uint4 q; bf16x8 v; };

// pack two fp32 into one dword of two truncated bf16 (elem a = low half)
__device__ __forceinline__ uint32_t hi2(float a, float b) {
    return (__float_as_uint(a) >> 16) | (__float_as_uint(b) & 0xffff0000u);
}
// residual after bf16 truncation (exact in fp32)
__device__ __forceinline__ float losub(float x) {
    return x - __uint_as_float(__float_as_uint(x) & 0xffff0000u);
}

// ---------------------------------------------------------------------------
// k_prep_x: fp32 x[64][4096] -> bf16 hi/lo arrays in MFMA A-fragment order.
// uint4 index = (mt*128 + kc)*64 + lane ; elem j: x[mt*16+(lane&15)][kc*32+(lane>>4)*8+j]
// ---------------------------------------------------------------------------
__global__ __launch_bounds__(256) void k_prep_x(const float* __restrict__ x,
        unsigned short* __restrict__ xh, unsigned short* __restrict__ xl) {
    int idx  = blockIdx.x * 256 + threadIdx.x;          // 0..262143
    int j    = idx & 7;
    int lane = (idx >> 3) & 63;
    int kc   = (idx >> 9) & 127;
    int mt   = idx >> 16;
    int row  = mt * 16 + (lane & 15);
    int col  = kc * 32 + ((lane >> 4) << 3) + j;
    float v  = x[(size_t)row * INF + col];
    uint32_t u = __float_as_uint(v);
    float lo = losub(v);
    xh[idx] = (unsigned short)(u >> 16);
    xl[idx] = (unsigned short)(__float_as_uint(lo) >> 16);
}

// ---------------------------------------------------------------------------
// k_lora_t: tm[t][r] = sum_k x[t][k] * A[r][k].  grid (64 tokens, 4 rgroups),
// one wave per (t,r); fully unrolled -> 32 independent loads in flight.
// ---------------------------------------------------------------------------
__global__ __launch_bounds__(256) void k_lora_t(const float* __restrict__ x,
        const float* __restrict__ A, float* __restrict__ tm) {
    int t = blockIdx.x, wv = threadIdx.x >> 6, lane = threadIdx.x & 63;
    int r = blockIdx.y * 4 + wv;
    const float4* xr = (const float4*)(x + (size_t)t * INF);
    const float4* ar = (const float4*)(A + (size_t)r * INF);
    float s = 0.f;
#pragma unroll
    for (int i = 0; i < INF / 4 / 64; ++i) {
        float4 a = xr[lane + i * 64], b = ar[lane + i * 64];
        s += a.x * b.x + a.y * b.y + a.z * b.z + a.w * b.w;
    }
#pragma unroll
    for (int off = 32; off > 0; off >>= 1) s += __shfl_down(s, off);
    if (lane == 0) tm[t * 16 + r] = s;
}

// ---------------------------------------------------------------------------
// k_main: y = x @ W^T via 16x16x32 bf16 MFMA, fp32 emulated hi/lo:
//   x*w ~= xh*wh + xh*wl + xl*wh
// KEY: x fragments go through LDS (lgkmcnt) so the per-kc MFMA dependency
// never drains the W vmcnt queue; W rides a fully-issued 16-load ring.
// ---------------------------------------------------------------------------
template<int QCNT, bool ATOMIC>
__global__ __launch_bounds__(256, 2) void k_main(const float* __restrict__ W,
        const uint4* __restrict__ xh, const uint4* __restrict__ xl,
        const float* __restrict__ scale, float* __restrict__ part,
        float* __restrict__ out) {
    constexpr int KC  = KCHUNKS / QCNT;  // kc chunks per block
    constexpr int SKC = 8;               // kc per stage
    constexpr int NST = KC / SKC;        // stages per block
    static_assert(KC % SKC == 0, "");
    __shared__ uint4 xs[2][4][SKC][64];  // 64 KB: [hi/lo][mt][kc][lane]

    int tid  = threadIdx.x;
    int lane = tid & 63;
    int wv   = tid >> 6;
    int nb   = blockIdx.x % NBLK;
    int q    = blockIdx.x / NBLK;
    int orow = nb * 64 + wv * 16 + (lane & 15);
    int quad = lane >> 4;

    const float* wp = W + (size_t)orow * INF + (size_t)q * (KC * 32) + quad * 8;

    floatx4 acc[4] = {};

    for (int st = 0; st < NST; ++st) {
        int kc0 = st * SKC;
        if (st > 0) __syncthreads();   // LDS reads of prev stage done

        // ---- stage x frags into LDS. Loads issued FIRST (before W ring)
        //      so the ds_write vmcnt wait leaves the W ring untouched. ----
        constexpr int CPT = (2 * 4 * SKC * 64) / 256;   // 16 uint4 per thread
        uint4 tmp[CPT];
#pragma unroll
        for (int it = 0; it < CPT; ++it) {
            int idx = tid + it * 256;
            int l2 = idx & 63, kc = (idx >> 6) & (SKC - 1);
            int mt = (idx >> 9) & 3, hl = idx >> 11;
            const uint4* src = hl ? xl : xh;
            tmp[it] = src[((size_t)mt * KCHUNKS + q * KC + kc0 + kc) * 64 + l2];
        }
#pragma unroll
        for (int it = 0; it < CPT; ++it) {
            int idx = tid + it * 256;
            int l2 = idx & 63, kc = (idx >> 6) & (SKC - 1);
            int mt = (idx >> 9) & 3, hl = idx >> 11;
            xs[hl][mt][kc][l2] = tmp[it];
        }

        // ---- issue the whole W ring for this stage (16 dwordx4, vmcnt) ----
        float4 wA[SKC], wB[SKC];
#pragma unroll
        for (int d = 0; d < SKC; ++d) {
            wA[d] = *(const float4*)(wp + (size_t)(kc0 + d) * 32);
            wB[d] = *(const float4*)(wp + (size_t)(kc0 + d) * 32 + 4);
        }

        __syncthreads();

        // ---- compute: 8 kc, x via ds_read (lgkmcnt), W from ring ----
#pragma unroll
        for (int d = 0; d < SKC; ++d) {
            float4 w0 = wA[d], w1 = wB[d];
            B8u wh, wl;
            wh.u[0] = hi2(w0.x, w0.y);  wh.u[1] = hi2(w0.z, w0.w);
            wh.u[2] = hi2(w1.x, w1.y);  wh.u[3] = hi2(w1.z, w1.w);
            wl.u[0] = hi2(losub(w0.x), losub(w0.y));
            wl.u[1] = hi2(losub(w0.z), losub(w0.w));
            wl.u[2] = hi2(losub(w1.x), losub(w1.y));
            wl.u[3] = hi2(losub(w1.z), losub(w1.w));
#pragma unroll
            for (int mt = 0; mt < 4; ++mt) {
                B8u ah, al;
                ah.q = xs[0][mt][d][lane];
                al.q = xs[1][mt][d][lane];
                acc[mt] = __builtin_amdgcn_mfma_f32_16x16x32_bf16(ah.v, wh.v, acc[mt], 0, 0, 0);
                acc[mt] = __builtin_amdgcn_mfma_f32_16x16x32_bf16(ah.v, wl.v, acc[mt], 0, 0, 0);
                acc[mt] = __builtin_amdgcn_mfma_f32_16x16x32_bf16(al.v, wh.v, acc[mt], 0, 0, 0);
            }
        }
    }

    // C/D layout (16x16, m89): col = lane&15 (= channel), row = quad*4 + reg (= token)
#pragma unroll
    for (int mt = 0; mt < 4; ++mt) {
        int token = mt * 16 + quad * 4;
#pragma unroll
        for (int r = 0; r < 4; ++r) {
            if constexpr (ATOMIC) {
                atomicAdd(&out[(size_t)(token + r) * OUTF + orow], scale[orow] * acc[mt][r]);
            } else {
                part[((size_t)q * TOK + token + r) * OUTF + orow] = acc[mt][r];
            }
        }
    }
}

// ---------------------------------------------------------------------------
// k_post: out[t][o] = scale[o]*sum_q part[q][t][o] + sum_r tm[t][r]*B[o][r] + bias[o]
// ---------------------------------------------------------------------------
template<int QCNT>
__global__ __launch_bounds__(256) void k_post(const float* __restrict__ part,
        const float* __restrict__ scale, const float* __restrict__ bias,
        const float* __restrict__ lB, const float* __restrict__ tm,
        float* __restrict__ out) {
    int o = blockIdx.x * 256 + threadIdx.x;
    int t = blockIdx.y;
    if (o >= OUTF) return;
    float s = 0.f;
#pragma unroll
    for (int qq = 0; qq < QCNT; ++qq)
        s += part[((size_t)qq * TOK + t) * OUTF + o];
    const float4* Br = (const float4*)(lB + (size_t)o * 16);
    const float4* tr = (const float4*)(tm + (size_t)t * 16);
    float l = 0.f;
#pragma unroll
    for (int i = 0; i < 4; ++i) {
        float4 b = Br[i], tt = tr[i];
        l += b.x * tt.x + b.y * tt.y + b.z * tt.z + b.w * tt.w;
    }
    out[(size_t)t * OUTF + o] = s * scale[o] + l + bias[o];
}

// Fallback pre-init for the atomic path: out = lora + bias, main adds scale*y.
__global__ __launch_bounds__(256) void k_pre(const float* __restrict__ bias,
        const float* __restrict__ lB, const float* __restrict__ tm,
        float* __restrict__ out) {
    int o = blockIdx.x * 256 + threadIdx.x;
    int t = blockIdx.y;
    if (o >= OUTF) return;
    const float4* Br = (const float4*)(lB + (size_t)o * 16);
    const float4* tr = (const float4*)(tm + (size_t)t * 16);
    float l = 0.f;
#pragma unroll
    for (int i = 0; i < 4; ++i) {
        float4 b = Br[i], tt = tr[i];
        l += b.x * tt.x + b.y * tt.y + b.z * tt.z + b.w * tt.w;
    }
    out[(size_t)t * OUTF + o] = l + bias[o];
}

extern "C" void kernel_launch(void* const* d_in, const int* in_sizes, int n_in,
                              void* d_out, int out_size, void* d_ws, size_t ws_size,
                              hipStream_t stream) {
    const float* x     = (const float*)d_in[0];
    const float* W     = (const float*)d_in[1];
    const float* scale = (const float*)d_in[2];
    const float* lA    = (const float*)d_in[3];
    const float* lB    = (const float*)d_in[4];
    const float* bias  = (const float*)d_in[5];
    float* out = (float*)d_out;

    char* ws = (char*)d_ws;
    unsigned short* xh = (unsigned short*)(ws);            // 512 KB
    unsigned short* xl = (unsigned short*)(ws + 524288);   // 512 KB
    float* tm   = (float*)(ws + 1048576);                  // 4 KB
    float* part = (float*)(ws + 1052672);
    const size_t base_ws = 1052672;
    const size_t need8 = base_ws + 8ull * TOK * OUTF * 4;  // 23.6 MB (R2 confirmed fits)
    const size_t need4 = base_ws + 4ull * TOK * OUTF * 4;  // 12.3 MB

    k_prep_x<<<1024, 256, 0, stream>>>(x, xh, xl);
    k_lora_t<<<dim3(TOK, 4), 256, 0, stream>>>(x, lA, tm);

    if (ws_size >= need8) {
        k_main<8, false><<<NBLK * 8, 256, 0, stream>>>(W, (const uint4*)xh,
                (const uint4*)xl, scale, part, out);
        k_post<8><<<dim3(43, TOK), 256, 0, stream>>>(part, scale, bias, lB, tm, out);
    } else if (ws_size >= need4) {
        k_main<4, false><<<NBLK * 4, 256, 0, stream>>>(W, (const uint4*)xh,
                (const uint4*)xl, scale, part, out);
        k_post<4><<<dim3(43, TOK), 256, 0, stream>>>(part, scale, bias, lB, tm, out);
    } else {
        k_pre<<<dim3(43, TOK), 256, 0, stream>>>(bias, lB, tm, out);
        k_main<8, true><<<NBLK * 8, 256, 0, stream>>>(W, (const uint4*)xh,
                (const uint4*)xl, scale, nullptr, out);
    }
}